// Round 1
// baseline (448.905 us; speedup 1.0000x reference)
//
#include <hip/hip_runtime.h>
#include <hip/hip_bf16.h>

typedef _Float16 h2_t __attribute__((ext_vector_type(2)));

__device__ __forceinline__ float fdot2(h2_t a, h2_t b, float c) {
#if __has_builtin(__builtin_amdgcn_fdot2)
    return __builtin_amdgcn_fdot2(a, b, c, false);
#else
    return c + (float)a.x * (float)b.x + (float)a.y * (float)b.y;
#endif
}

// ---------------------------------------------------------------------------
// Kernel 1: fused conv1(s2,SAME,3x3,5->32)+relu -> conv2(s2,SAME,3x3,32->64)
//           +relu -> global average pool.  One block per frame (n = b*T+t).
// JAX SAME pad for even in, stride 2, k=3: pad_total=1 -> (lo=0, hi=1),
// so input window rows are ih = 2*oh + ky  (NO -1), skip ih >= size.
// ---------------------------------------------------------------------------
__global__ __launch_bounds__(512) void k_conv(
    const float* __restrict__ x,   // [512][64][64][5]
    const float* __restrict__ w1,  // [3][3][5][32]
    const float* __restrict__ b1,  // [32]
    const float* __restrict__ w2,  // [3][3][32][64]
    const float* __restrict__ b2,  // [64]
    float* __restrict__ pooled)    // [512][64]
{
    __shared__ _Float16 xs[5 * 64 * 64];    // [c][h][w]  40 KB
    __shared__ _Float16 c1s[32 * 32 * 32];  // [c][h][w]  64 KB
    __shared__ float pl[256];               // 8 waves x 32 ch partials

    const int n = blockIdx.x;
    const int tid = threadIdx.x;

    // ---- stage x frame to LDS (f16), layout [c][pixel] ----
    const float* xf = x + (size_t)n * 20480;
    for (int i = tid; i < 20480; i += 512) {
        int c = i % 5, p = i / 5;           // NHWC: i = pixel*5 + c
        xs[c * 4096 + p] = (_Float16)xf[i];
    }
    __syncthreads();

    // ---- conv1: 32x32 out pixels, 32 oc; 2 pixels per thread ----
    for (int pp = 0; pp < 2; ++pp) {
        int p = tid + pp * 512;
        int oh = p >> 5, ow = p & 31;
        float acc[32];
#pragma unroll
        for (int oc = 0; oc < 32; ++oc) acc[oc] = b1[oc];
        for (int ky = 0; ky < 3; ++ky) {
            int ih = 2 * oh + ky;
            if (ih < 64) {
                for (int kx = 0; kx < 3; ++kx) {
                    int iw = 2 * ow + kx;
                    if (iw < 64) {
#pragma unroll
                        for (int c = 0; c < 5; ++c) {
                            float v = (float)xs[c * 4096 + ih * 64 + iw];
                            const float* wp = w1 + ((ky * 3 + kx) * 5 + c) * 32;
#pragma unroll
                            for (int oc = 0; oc < 32; ++oc)
                                acc[oc] = fmaf(v, wp[oc], acc[oc]);
                        }
                    }
                }
            }
        }
#pragma unroll
        for (int oc = 0; oc < 32; ++oc) {
            float r = acc[oc] > 0.f ? acc[oc] : 0.f;
            c1s[oc * 1024 + p] = (_Float16)r;
        }
    }
    __syncthreads();

    // ---- conv2 + relu + pool.  256 out pixels (16x16), 64 oc.
    // thread: pixel = tid & 255, oc-half = tid >> 8  (wave-uniform ocbase ->
    // scalar weight loads).
    {
        const int p = tid & 255;
        const int oh = p >> 4, ow = p & 15;
        const int ocbase = (tid >> 8) * 32;   // uniform within a wave
        float acc[32];
#pragma unroll
        for (int j = 0; j < 32; ++j) acc[j] = b2[ocbase + j];
        for (int ky = 0; ky < 3; ++ky) {
            int ih = 2 * oh + ky;
            if (ih < 32) {
                for (int kx = 0; kx < 3; ++kx) {
                    int iw = 2 * ow + kx;
                    if (iw < 32) {
#pragma unroll 4
                        for (int c = 0; c < 32; ++c) {
                            float v = (float)c1s[c * 1024 + ih * 32 + iw];
                            const float* wp =
                                w2 + (((ky * 3 + kx) * 32 + c) * 64) + ocbase;
#pragma unroll
                            for (int j = 0; j < 32; ++j)
                                acc[j] = fmaf(v, wp[j], acc[j]);
                        }
                    }
                }
            }
        }
        // relu
#pragma unroll
        for (int j = 0; j < 32; ++j) acc[j] = acc[j] > 0.f ? acc[j] : 0.f;
        // reduce over the wave's 64 pixels (same ocbase across the wave)
#pragma unroll
        for (int off = 1; off <= 32; off <<= 1) {
#pragma unroll
            for (int j = 0; j < 32; ++j)
                acc[j] += __shfl_xor(acc[j], off, 64);
        }
        const int lane = tid & 63, wv = tid >> 6;
        if (lane == 0) {
#pragma unroll
            for (int j = 0; j < 32; ++j) pl[wv * 32 + j] = acc[j];
        }
    }
    __syncthreads();
    if (tid < 64) {
        int half = tid >> 5, j = tid & 31;
        float s = 0.f;
#pragma unroll
        for (int i = 0; i < 4; ++i) s += pl[(half * 4 + i) * 32 + j];
        pooled[n * 64 + tid] = s * (1.0f / 256.0f);
    }
}

// ---------------------------------------------------------------------------
// Kernel 2: feats = relu(pooled @ dw + db) ; xg = feats @ wx + b_gru.
// One block per 4 frame-rows.
// ---------------------------------------------------------------------------
__global__ __launch_bounds__(256) void k_dense(
    const float* __restrict__ pooled,  // [512][64]
    const float* __restrict__ dw,      // [64][256]
    const float* __restrict__ db,      // [256]
    const float* __restrict__ wx,      // [256][768]
    const float* __restrict__ bg,      // [768]
    float* __restrict__ xg)            // [512][768]
{
    __shared__ float ps[4 * 64];
    __shared__ float fs[4 * 256];
    const int tid = threadIdx.x;
    const int r0 = blockIdx.x * 4;

    ps[tid & 255] = pooled[r0 * 64 + (tid & 255)];
    __syncthreads();

    {
        float a0 = db[tid], a1 = a0, a2 = a0, a3 = a0;
        for (int k = 0; k < 64; ++k) {
            float w = dw[k * 256 + tid];
            a0 = fmaf(ps[0 * 64 + k], w, a0);
            a1 = fmaf(ps[1 * 64 + k], w, a1);
            a2 = fmaf(ps[2 * 64 + k], w, a2);
            a3 = fmaf(ps[3 * 64 + k], w, a3);
        }
        fs[0 * 256 + tid] = fmaxf(a0, 0.f);
        fs[1 * 256 + tid] = fmaxf(a1, 0.f);
        fs[2 * 256 + tid] = fmaxf(a2, 0.f);
        fs[3 * 256 + tid] = fmaxf(a3, 0.f);
    }
    __syncthreads();

    float acc[3][4];
#pragma unroll
    for (int g = 0; g < 3; ++g) {
        float b = bg[g * 256 + tid];
#pragma unroll
        for (int r = 0; r < 4; ++r) acc[g][r] = b;
    }
    for (int k = 0; k < 256; ++k) {
        float f0 = fs[0 * 256 + k], f1 = fs[1 * 256 + k];
        float f2 = fs[2 * 256 + k], f3 = fs[3 * 256 + k];
#pragma unroll
        for (int g = 0; g < 3; ++g) {
            float w = wx[k * 768 + g * 256 + tid];
            acc[g][0] = fmaf(f0, w, acc[g][0]);
            acc[g][1] = fmaf(f1, w, acc[g][1]);
            acc[g][2] = fmaf(f2, w, acc[g][2]);
            acc[g][3] = fmaf(f3, w, acc[g][3]);
        }
    }
#pragma unroll
    for (int r = 0; r < 4; ++r)
#pragma unroll
        for (int g = 0; g < 3; ++g)
            xg[(size_t)(r0 + r) * 768 + g * 256 + tid] = acc[g][r];
}

// ---------------------------------------------------------------------------
// Kernel 3: GRU scan.  One block per batch row, 512 threads (8 waves).
// Weights register-resident as f16: lane holds 128 k-values for one column of
// each gate (192 VGPRs).  col = wv*32 + (lane&31); kc = lane>>5 selects the
// 128-row k-chunk; one shfl_xor(32) completes each dot product.
// ---------------------------------------------------------------------------
__global__ __launch_bounds__(512) void k_gru(
    const float* __restrict__ xg,   // [512][768]  (b*32+t major)
    const float* __restrict__ wh,   // [256][768]  [z|r|h]
    float* __restrict__ out)        // [16*32*256] seq ++ [16*256] state
{
    __shared__ float hf[256];
    __shared__ _Float16 hh[256];
    __shared__ _Float16 rhh[256];

    const int b = blockIdx.x;
    const int tid = threadIdx.x;
    const int lane = tid & 63, wv = tid >> 6;
    const int col = wv * 32 + (lane & 31);
    const int kc = lane >> 5;
    const int k0 = kc * 128;

    h2_t wz[64], wr[64], wc[64];
#pragma unroll
    for (int j = 0; j < 64; ++j) {
        int k = k0 + 2 * j;
        wz[j] = h2_t{(_Float16)wh[k * 768 + col],
                     (_Float16)wh[(k + 1) * 768 + col]};
        wr[j] = h2_t{(_Float16)wh[k * 768 + col + 256],
                     (_Float16)wh[(k + 1) * 768 + col + 256]};
        wc[j] = h2_t{(_Float16)wh[k * 768 + col + 512],
                     (_Float16)wh[(k + 1) * 768 + col + 512]};
    }

    if (tid < 256) { hf[tid] = 0.f; hh[tid] = (_Float16)0.f; }
    __syncthreads();

    const h2_t* hh2 = (const h2_t*)hh;
    const h2_t* rh2 = (const h2_t*)rhh;
    float* outb = out + (size_t)b * 32 * 256;

    for (int t = 0; t < 32; ++t) {
        const float* xrow = xg + (size_t)(b * 32 + t) * 768;
        float xz = xrow[col], xr = xrow[col + 256], xh = xrow[col + 512];

        float az = 0.f, ar = 0.f;
#pragma unroll
        for (int j = 0; j < 64; ++j) {
            h2_t h = hh2[kc * 64 + j];
            az = fdot2(wz[j], h, az);
            ar = fdot2(wr[j], h, ar);
        }
        az += __shfl_xor(az, 32, 64);
        ar += __shfl_xor(ar, 32, 64);
        float hold = hf[col];
        float z = 1.f / (1.f + __expf(-(az + xz)));
        float r = 1.f / (1.f + __expf(-(ar + xr)));
        __syncthreads();                       // B1: all h reads done
        if (kc == 0) rhh[col] = (_Float16)(r * hold);
        __syncthreads();                       // B2: rh visible

        float ah = 0.f;
#pragma unroll
        for (int j = 0; j < 64; ++j)
            ah = fdot2(wc[j], rh2[kc * 64 + j], ah);
        ah += __shfl_xor(ah, 32, 64);
        float sx = ah + xh;
        sx = fminf(fmaxf(sx, -15.f), 15.f);
        float e = __expf(2.f * sx);
        float hc = (e - 1.f) / (e + 1.f);      // tanh
        float hn = z * hold + (1.f - z) * hc;

        if (kc == 0) {
            hf[col] = hn;
            hh[col] = (_Float16)hn;
            outb[t * 256 + col] = hn;
            if (t == 31) out[16 * 32 * 256 + b * 256 + col] = hn;
        }
        __syncthreads();                       // B3: h update visible,
                                               // rh reads done before next write
    }
}

// ---------------------------------------------------------------------------
extern "C" void kernel_launch(void* const* d_in, const int* in_sizes, int n_in,
                              void* d_out, int out_size, void* d_ws,
                              size_t ws_size, hipStream_t stream)
{
    const float* x  = (const float*)d_in[0];
    const float* w1 = (const float*)d_in[1];
    const float* b1 = (const float*)d_in[2];
    const float* w2 = (const float*)d_in[3];
    const float* b2 = (const float*)d_in[4];
    const float* dw = (const float*)d_in[5];
    const float* db = (const float*)d_in[6];
    const float* wx = (const float*)d_in[7];
    const float* wh = (const float*)d_in[8];
    const float* bg = (const float*)d_in[9];
    float* out = (float*)d_out;

    float* pooled = (float*)d_ws;          // 512*64 f32
    float* xg = pooled + 512 * 64;         // 512*768 f32  (~1.7 MB total ws)

    k_conv<<<512, 512, 0, stream>>>(x, w1, b1, w2, b2, pooled);
    k_dense<<<128, 256, 0, stream>>>(pooled, dw, db, wx, bg, xg);
    k_gru<<<16, 512, 0, stream>>>(xg, wh, out);
}

// Round 2
// 183.296 us; speedup vs baseline: 2.4491x; 2.4491x over previous
//
#include <hip/hip_runtime.h>
#include <hip/hip_bf16.h>

typedef _Float16 h2_t  __attribute__((ext_vector_type(2)));
typedef _Float16 f16x8 __attribute__((ext_vector_type(8)));
typedef float    f32x4 __attribute__((ext_vector_type(4)));

__device__ __forceinline__ float fdot2(h2_t a, h2_t b, float c) {
#if __has_builtin(__builtin_amdgcn_fdot2)
    return __builtin_amdgcn_fdot2(a, b, c, false);
#else
    return c + (float)a.x * (float)b.x + (float)a.y * (float)b.y;
#endif
}

__device__ __forceinline__ unsigned pack2(float lo, float hi) {
    union { h2_t h; unsigned u; } cv;
    cv.h.x = (_Float16)lo; cv.h.y = (_Float16)hi;
    return cv.u;
}

// ---------------------------------------------------------------------------
// Prep: w2 [9*32][64] f32  ->  B-fragments w2f[tap][ntile][lane] = f16x8
// lane l of ntile nt holds B[k=c][col=oc]: oc = nt*16 + (l&15),
// c = (l>>4)*8 + j  (j=0..7)  — mfma_f32_16x16x32_f16 B layout.
// ---------------------------------------------------------------------------
__global__ __launch_bounds__(256) void k_w2prep(
    const float* __restrict__ w2, f16x8* __restrict__ w2f)
{
    int idx = blockIdx.x * 256 + threadIdx.x;   // 9*4*64 = 2304
    if (idx >= 9 * 4 * 64) return;
    int lane = idx & 63;
    int nt   = (idx >> 6) & 3;
    int tap  = idx >> 8;
    int oc = nt * 16 + (lane & 15);
    int c0 = (lane >> 4) * 8;
    f16x8 v;
#pragma unroll
    for (int j = 0; j < 8; ++j)
        v[j] = (_Float16)w2[(tap * 32 + c0 + j) * 64 + oc];
    w2f[idx] = v;
}

// ---------------------------------------------------------------------------
// Fused conv1(VALU) + conv2(MFMA) + global-average-pool.  1 block = 1 frame.
// 512 threads = 8 waves.  LDS ~70 KB -> 2 blocks/CU -> 4 waves/SIMD.
// SAME pad, stride 2, even size: ih = 2*oh + ky (pad lo=0, hi=1).
// ---------------------------------------------------------------------------
__global__ __launch_bounds__(512, 4) void k_conv(
    const float* __restrict__ x,    // [512][64][64][5]
    const float* __restrict__ w1,   // [3][3][5][32]
    const float* __restrict__ b1,   // [32]
    const f16x8* __restrict__ w2f,  // [9][4][64] B-frags
    const float* __restrict__ b2,   // [64]
    float* __restrict__ pooled)     // [512][64]
{
    __shared__ _Float16 c1s[32 * 33 * 32];   // [ih][iw(+pad col 32)][c] 67.6 KB
    __shared__ float pl[8 * 64];             // per-wave pooled partials

    const int n = blockIdx.x;
    const int tid = threadIdx.x;
    const int lane = tid & 63, wv = tid >> 6;

    // zero the iw==32 pad column (read when ow=15 & kx=2 in conv2)
    {
        int r = tid >> 4, d = tid & 15;      // 32 rows x 16 dwords = 512
        ((unsigned*)c1s)[(r * 33 + 32) * 16 + d] = 0u;
    }

    const float* xf = x + (size_t)n * 20480;

    // ---- conv1: 1024 out pixels (32x32), 32 oc; 2 pixels per thread ----
    for (int pp = 0; pp < 2; ++pp) {
        int p = tid + pp * 512;
        int oh = p >> 5, ow = p & 31;
        float acc[32];
#pragma unroll
        for (int oc = 0; oc < 32; ++oc) acc[oc] = b1[oc];
#pragma unroll
        for (int ky = 0; ky < 3; ++ky) {
            int ih = 2 * oh + ky;
            if (ih < 64) {
                const float* rb = xf + (ih * 64 + 2 * ow) * 5;  // 8B-aligned
                float xv[15];                 // (kx,c) flattened, contiguous
                const float2* rb2 = (const float2*)rb;
#pragma unroll
                for (int q = 0; q < 5; ++q) {
                    float2 v = rb2[q];
                    xv[2 * q] = v.x; xv[2 * q + 1] = v.y;
                }
                if (ow < 31) {                // kx=2 in-bounds
                    float2 v5 = rb2[5], v6 = rb2[6];
                    xv[10] = v5.x; xv[11] = v5.y;
                    xv[12] = v6.x; xv[13] = v6.y;
                    xv[14] = rb[14];
                } else {                      // iw=64 -> SAME pad zeros
                    xv[10] = xv[11] = xv[12] = xv[13] = xv[14] = 0.f;
                }
#pragma unroll
                for (int q = 0; q < 15; ++q) {
                    float v = xv[q];
                    const float* wp = w1 + (ky * 15 + q) * 32;  // uniform
#pragma unroll
                    for (int oc = 0; oc < 32; ++oc)
                        acc[oc] = fmaf(v, wp[oc], acc[oc]);
                }
            }
        }
        // relu -> f16 pack -> LDS [oh][ow][c] (64B/pixel, b128 writes)
        unsigned* dst = (unsigned*)&c1s[(oh * 33 + ow) * 32];
#pragma unroll
        for (int j = 0; j < 16; ++j)
            dst[j] = pack2(fmaxf(acc[2 * j], 0.f), fmaxf(acc[2 * j + 1], 0.f));
    }
    __syncthreads();

    // ---- conv2 as implicit GEMM via MFMA: M=256 px, N=64 oc, K=9x32 ----
    // wave wv owns mtiles oh2 = {wv, wv+8}; A row = ow2 = lane&15,
    // k = c = (lane>>4)*8 + j.
    f32x4 acc2[2][4];
#pragma unroll
    for (int mt = 0; mt < 2; ++mt)
#pragma unroll
        for (int nt = 0; nt < 4; ++nt) acc2[mt][nt] = f32x4{0.f, 0.f, 0.f, 0.f};

    const int owl = lane & 15;
    const int cb = (lane >> 4) * 8;
#pragma unroll
    for (int tap = 0; tap < 9; ++tap) {
        const int ky = tap / 3, kx = tap % 3;
        f16x8 bf[4];
#pragma unroll
        for (int nt = 0; nt < 4; ++nt)
            bf[nt] = w2f[(tap * 4 + nt) * 64 + lane];
#pragma unroll
        for (int mt = 0; mt < 2; ++mt) {
            int oh2 = wv + mt * 8;
            int ih = 2 * oh2 + ky;
            if (ih < 32) {                    // wave-uniform; ih=32 = pad row
                int iw = 2 * owl + kx;        // <=32; 32 hits zeroed pad col
                f16x8 af = *(const f16x8*)&c1s[(ih * 33 + iw) * 32 + cb];
#pragma unroll
                for (int nt = 0; nt < 4; ++nt)
                    acc2[mt][nt] = __builtin_amdgcn_mfma_f32_16x16x32_f16(
                        af, bf[nt], acc2[mt][nt], 0, 0, 0);
            }
        }
    }

    // ---- bias + relu + pool.  C layout: col=lane&15 (oc), row=(lane>>4)*4+r
#pragma unroll
    for (int nt = 0; nt < 4; ++nt) {
        float b = b2[nt * 16 + owl];
        float s = 0.f;
#pragma unroll
        for (int mt = 0; mt < 2; ++mt)
#pragma unroll
            for (int r = 0; r < 4; ++r)
                s += fmaxf(acc2[mt][nt][r] + b, 0.f);
        s += __shfl_xor(s, 16, 64);
        s += __shfl_xor(s, 32, 64);
        if (lane < 16) pl[wv * 64 + nt * 16 + lane] = s;
    }
    __syncthreads();
    if (tid < 64) {
        float s = 0.f;
#pragma unroll
        for (int w = 0; w < 8; ++w) s += pl[w * 64 + tid];
        pooled[n * 64 + tid] = s * (1.0f / 256.0f);
    }
}

// ---------------------------------------------------------------------------
// Dense: feats = relu(pooled @ dw + db);  xg = feats @ wx + b_gru.
// ---------------------------------------------------------------------------
__global__ __launch_bounds__(256) void k_dense(
    const float* __restrict__ pooled,  // [512][64]
    const float* __restrict__ dw,      // [64][256]
    const float* __restrict__ db,      // [256]
    const float* __restrict__ wx,      // [256][768]
    const float* __restrict__ bg,      // [768]
    float* __restrict__ xg)            // [512][768]
{
    __shared__ float ps[4 * 64];
    __shared__ float fs[4 * 256];
    const int tid = threadIdx.x;
    const int r0 = blockIdx.x * 4;

    ps[tid & 255] = pooled[r0 * 64 + (tid & 255)];
    __syncthreads();

    {
        float a0 = db[tid], a1 = a0, a2 = a0, a3 = a0;
        for (int k = 0; k < 64; ++k) {
            float w = dw[k * 256 + tid];
            a0 = fmaf(ps[0 * 64 + k], w, a0);
            a1 = fmaf(ps[1 * 64 + k], w, a1);
            a2 = fmaf(ps[2 * 64 + k], w, a2);
            a3 = fmaf(ps[3 * 64 + k], w, a3);
        }
        fs[0 * 256 + tid] = fmaxf(a0, 0.f);
        fs[1 * 256 + tid] = fmaxf(a1, 0.f);
        fs[2 * 256 + tid] = fmaxf(a2, 0.f);
        fs[3 * 256 + tid] = fmaxf(a3, 0.f);
    }
    __syncthreads();

    float acc[3][4];
#pragma unroll
    for (int g = 0; g < 3; ++g) {
        float b = bg[g * 256 + tid];
#pragma unroll
        for (int r = 0; r < 4; ++r) acc[g][r] = b;
    }
    for (int k = 0; k < 256; ++k) {
        float f0 = fs[0 * 256 + k], f1 = fs[1 * 256 + k];
        float f2 = fs[2 * 256 + k], f3 = fs[3 * 256 + k];
#pragma unroll
        for (int g = 0; g < 3; ++g) {
            float w = wx[k * 768 + g * 256 + tid];
            acc[g][0] = fmaf(f0, w, acc[g][0]);
            acc[g][1] = fmaf(f1, w, acc[g][1]);
            acc[g][2] = fmaf(f2, w, acc[g][2]);
            acc[g][3] = fmaf(f3, w, acc[g][3]);
        }
    }
#pragma unroll
    for (int r = 0; r < 4; ++r)
#pragma unroll
        for (int g = 0; g < 3; ++g)
            xg[(size_t)(r0 + r) * 768 + g * 256 + tid] = acc[g][r];
}

// ---------------------------------------------------------------------------
// GRU scan.  One block per batch row, 512 threads (8 waves), weights
// register-resident f16, shfl_xor(32) completes each dot product.
// ---------------------------------------------------------------------------
__global__ __launch_bounds__(512) void k_gru(
    const float* __restrict__ xg,   // [512][768]
    const float* __restrict__ wh,   // [256][768]  [z|r|h]
    float* __restrict__ out)        // [16*32*256] seq ++ [16*256] state
{
    __shared__ float hf[256];
    __shared__ _Float16 hh[256];
    __shared__ _Float16 rhh[256];

    const int b = blockIdx.x;
    const int tid = threadIdx.x;
    const int lane = tid & 63, wv = tid >> 6;
    const int col = wv * 32 + (lane & 31);
    const int kc = lane >> 5;
    const int k0 = kc * 128;

    h2_t wz[64], wr[64], wc[64];
#pragma unroll
    for (int j = 0; j < 64; ++j) {
        int k = k0 + 2 * j;
        wz[j] = h2_t{(_Float16)wh[k * 768 + col],
                     (_Float16)wh[(k + 1) * 768 + col]};
        wr[j] = h2_t{(_Float16)wh[k * 768 + col + 256],
                     (_Float16)wh[(k + 1) * 768 + col + 256]};
        wc[j] = h2_t{(_Float16)wh[k * 768 + col + 512],
                     (_Float16)wh[(k + 1) * 768 + col + 512]};
    }

    if (tid < 256) { hf[tid] = 0.f; hh[tid] = (_Float16)0.f; }
    __syncthreads();

    const h2_t* hh2 = (const h2_t*)hh;
    const h2_t* rh2 = (const h2_t*)rhh;
    float* outb = out + (size_t)b * 32 * 256;

    for (int t = 0; t < 32; ++t) {
        const float* xrow = xg + (size_t)(b * 32 + t) * 768;
        float xz = xrow[col], xr = xrow[col + 256], xh = xrow[col + 512];

        float az = 0.f, ar = 0.f;
#pragma unroll
        for (int j = 0; j < 64; ++j) {
            h2_t h = hh2[kc * 64 + j];
            az = fdot2(wz[j], h, az);
            ar = fdot2(wr[j], h, ar);
        }
        az += __shfl_xor(az, 32, 64);
        ar += __shfl_xor(ar, 32, 64);
        float hold = hf[col];
        float z = 1.f / (1.f + __expf(-(az + xz)));
        float r = 1.f / (1.f + __expf(-(ar + xr)));
        __syncthreads();                       // B1: all h reads done
        if (kc == 0) rhh[col] = (_Float16)(r * hold);
        __syncthreads();                       // B2: rh visible

        float ah = 0.f;
#pragma unroll
        for (int j = 0; j < 64; ++j)
            ah = fdot2(wc[j], rh2[kc * 64 + j], ah);
        ah += __shfl_xor(ah, 32, 64);
        float sx = ah + xh;
        sx = fminf(fmaxf(sx, -15.f), 15.f);
        float e = __expf(2.f * sx);
        float hc = (e - 1.f) / (e + 1.f);      // tanh
        float hn = z * hold + (1.f - z) * hc;

        if (kc == 0) {
            hf[col] = hn;
            hh[col] = (_Float16)hn;
            outb[t * 256 + col] = hn;
            if (t == 31) out[16 * 32 * 256 + b * 256 + col] = hn;
        }
        __syncthreads();                       // B3: h update visible
    }
}

// ---------------------------------------------------------------------------
extern "C" void kernel_launch(void* const* d_in, const int* in_sizes, int n_in,
                              void* d_out, int out_size, void* d_ws,
                              size_t ws_size, hipStream_t stream)
{
    const float* x  = (const float*)d_in[0];
    const float* w1 = (const float*)d_in[1];
    const float* b1 = (const float*)d_in[2];
    const float* w2 = (const float*)d_in[3];
    const float* b2 = (const float*)d_in[4];
    const float* dw = (const float*)d_in[5];
    const float* db = (const float*)d_in[6];
    const float* wx = (const float*)d_in[7];
    const float* wh = (const float*)d_in[8];
    const float* bg = (const float*)d_in[9];
    float* out = (float*)d_out;

    float* pooled = (float*)d_ws;                  // 512*64 f32
    float* xg = pooled + 512 * 64;                 // 512*768 f32
    f16x8* w2f = (f16x8*)(xg + 512 * 768);         // 9*4*64 f16x8 (36.9 KB)

    k_w2prep<<<9, 256, 0, stream>>>(w2, w2f);
    k_conv<<<512, 512, 0, stream>>>(x, w1, b1, w2f, b2, pooled);
    k_dense<<<128, 256, 0, stream>>>(pooled, dw, db, wx, bg, xg);
    k_gru<<<16, 512, 0, stream>>>(xg, wh, out);
}

// Round 3
// 175.500 us; speedup vs baseline: 2.5579x; 1.0444x over previous
//
#include <hip/hip_runtime.h>
#include <hip/hip_bf16.h>

typedef _Float16 h2_t  __attribute__((ext_vector_type(2)));
typedef _Float16 f16x8 __attribute__((ext_vector_type(8)));
typedef float    f32x4 __attribute__((ext_vector_type(4)));

__device__ __forceinline__ float fdot2(h2_t a, h2_t b, float c) {
#if __has_builtin(__builtin_amdgcn_fdot2)
    return __builtin_amdgcn_fdot2(a, b, c, false);
#else
    return c + (float)a.x * (float)b.x + (float)a.y * (float)b.y;
#endif
}

__device__ __forceinline__ unsigned pack2(float lo, float hi) {
    union { h2_t h; unsigned u; } cv;
    cv.h.x = (_Float16)lo; cv.h.y = (_Float16)hi;
    return cv.u;
}

// ---------------------------------------------------------------------------
// Prep: w2 [9*32][64] f32 -> B-fragments for mfma_f32_16x16x32_f16.
// ---------------------------------------------------------------------------
__global__ __launch_bounds__(256) void k_w2prep(
    const float* __restrict__ w2, f16x8* __restrict__ w2f)
{
    int idx = blockIdx.x * 256 + threadIdx.x;   // 9*4*64 = 2304
    if (idx >= 9 * 4 * 64) return;
    int lane = idx & 63;
    int nt   = (idx >> 6) & 3;
    int tap  = idx >> 8;
    int oc = nt * 16 + (lane & 15);
    int c0 = (lane >> 4) * 8;
    f16x8 v;
#pragma unroll
    for (int j = 0; j < 8; ++j)
        v[j] = (_Float16)w2[(tap * 32 + c0 + j) * 64 + oc];
    w2f[idx] = v;
}

// ---------------------------------------------------------------------------
// Fused conv1(VALU) + conv2(MFMA) + global-average-pool.  1 block = 1 frame.
// ---------------------------------------------------------------------------
__global__ __launch_bounds__(512, 4) void k_conv(
    const float* __restrict__ x,    // [512][64][64][5]
    const float* __restrict__ w1,   // [3][3][5][32]
    const float* __restrict__ b1,   // [32]
    const f16x8* __restrict__ w2f,  // [9][4][64] B-frags
    const float* __restrict__ b2,   // [64]
    float* __restrict__ pooled)     // [512][64]
{
    __shared__ _Float16 c1s[32 * 33 * 32];   // [ih][iw(+pad)][c] 67.6 KB
    __shared__ float pl[8 * 64];

    const int n = blockIdx.x;
    const int tid = threadIdx.x;
    const int lane = tid & 63, wv = tid >> 6;

    {   // zero the iw==32 pad column
        int r = tid >> 4, d = tid & 15;
        ((unsigned*)c1s)[(r * 33 + 32) * 16 + d] = 0u;
    }

    const float* xf = x + (size_t)n * 20480;

    for (int pp = 0; pp < 2; ++pp) {
        int p = tid + pp * 512;
        int oh = p >> 5, ow = p & 31;
        float acc[32];
#pragma unroll
        for (int oc = 0; oc < 32; ++oc) acc[oc] = b1[oc];
#pragma unroll
        for (int ky = 0; ky < 3; ++ky) {
            int ih = 2 * oh + ky;
            if (ih < 64) {
                const float* rb = xf + (ih * 64 + 2 * ow) * 5;
                float xv[15];
                const float2* rb2 = (const float2*)rb;
#pragma unroll
                for (int q = 0; q < 5; ++q) {
                    float2 v = rb2[q];
                    xv[2 * q] = v.x; xv[2 * q + 1] = v.y;
                }
                if (ow < 31) {
                    float2 v5 = rb2[5], v6 = rb2[6];
                    xv[10] = v5.x; xv[11] = v5.y;
                    xv[12] = v6.x; xv[13] = v6.y;
                    xv[14] = rb[14];
                } else {
                    xv[10] = xv[11] = xv[12] = xv[13] = xv[14] = 0.f;
                }
#pragma unroll
                for (int q = 0; q < 15; ++q) {
                    float v = xv[q];
                    const float* wp = w1 + (ky * 15 + q) * 32;
#pragma unroll
                    for (int oc = 0; oc < 32; ++oc)
                        acc[oc] = fmaf(v, wp[oc], acc[oc]);
                }
            }
        }
        unsigned* dst = (unsigned*)&c1s[(oh * 33 + ow) * 32];
#pragma unroll
        for (int j = 0; j < 16; ++j)
            dst[j] = pack2(fmaxf(acc[2 * j], 0.f), fmaxf(acc[2 * j + 1], 0.f));
    }
    __syncthreads();

    // conv2 as implicit GEMM via MFMA: M=256 px, N=64 oc, K=9x32
    f32x4 acc2[2][4];
#pragma unroll
    for (int mt = 0; mt < 2; ++mt)
#pragma unroll
        for (int nt = 0; nt < 4; ++nt) acc2[mt][nt] = f32x4{0.f, 0.f, 0.f, 0.f};

    const int owl = lane & 15;
    const int cb = (lane >> 4) * 8;
#pragma unroll
    for (int tap = 0; tap < 9; ++tap) {
        const int ky = tap / 3, kx = tap % 3;
        f16x8 bf[4];
#pragma unroll
        for (int nt = 0; nt < 4; ++nt)
            bf[nt] = w2f[(tap * 4 + nt) * 64 + lane];
#pragma unroll
        for (int mt = 0; mt < 2; ++mt) {
            int oh2 = wv + mt * 8;
            int ih = 2 * oh2 + ky;
            if (ih < 32) {
                int iw = 2 * owl + kx;
                f16x8 af = *(const f16x8*)&c1s[(ih * 33 + iw) * 32 + cb];
#pragma unroll
                for (int nt = 0; nt < 4; ++nt)
                    acc2[mt][nt] = __builtin_amdgcn_mfma_f32_16x16x32_f16(
                        af, bf[nt], acc2[mt][nt], 0, 0, 0);
            }
        }
    }

#pragma unroll
    for (int nt = 0; nt < 4; ++nt) {
        float b = b2[nt * 16 + owl];
        float s = 0.f;
#pragma unroll
        for (int mt = 0; mt < 2; ++mt)
#pragma unroll
            for (int r = 0; r < 4; ++r)
                s += fmaxf(acc2[mt][nt][r] + b, 0.f);
        s += __shfl_xor(s, 16, 64);
        s += __shfl_xor(s, 32, 64);
        if (lane < 16) pl[wv * 64 + nt * 16 + lane] = s;
    }
    __syncthreads();
    if (tid < 64) {
        float s = 0.f;
#pragma unroll
        for (int w = 0; w < 8; ++w) s += pl[w * 64 + tid];
        pooled[n * 64 + tid] = s * (1.0f / 256.0f);
    }
}

// ---------------------------------------------------------------------------
// Dense: feats = relu(pooled @ dw + db);  xg = feats @ wx + b_gru.
// ---------------------------------------------------------------------------
__global__ __launch_bounds__(256) void k_dense(
    const float* __restrict__ pooled,  // [512][64]
    const float* __restrict__ dw,      // [64][256]
    const float* __restrict__ db,      // [256]
    const float* __restrict__ wx,      // [256][768]
    const float* __restrict__ bg,      // [768]
    float* __restrict__ xg)            // [512][768]
{
    __shared__ float ps[4 * 64];
    __shared__ float fs[4 * 256];
    const int tid = threadIdx.x;
    const int r0 = blockIdx.x * 4;

    ps[tid & 255] = pooled[r0 * 64 + (tid & 255)];
    __syncthreads();

    {
        float a0 = db[tid], a1 = a0, a2 = a0, a3 = a0;
        for (int k = 0; k < 64; ++k) {
            float w = dw[k * 256 + tid];
            a0 = fmaf(ps[0 * 64 + k], w, a0);
            a1 = fmaf(ps[1 * 64 + k], w, a1);
            a2 = fmaf(ps[2 * 64 + k], w, a2);
            a3 = fmaf(ps[3 * 64 + k], w, a3);
        }
        fs[0 * 256 + tid] = fmaxf(a0, 0.f);
        fs[1 * 256 + tid] = fmaxf(a1, 0.f);
        fs[2 * 256 + tid] = fmaxf(a2, 0.f);
        fs[3 * 256 + tid] = fmaxf(a3, 0.f);
    }
    __syncthreads();

    float acc[3][4];
#pragma unroll
    for (int g = 0; g < 3; ++g) {
        float b = bg[g * 256 + tid];
#pragma unroll
        for (int r = 0; r < 4; ++r) acc[g][r] = b;
    }
    for (int k = 0; k < 256; ++k) {
        float f0 = fs[0 * 256 + k], f1 = fs[1 * 256 + k];
        float f2 = fs[2 * 256 + k], f3 = fs[3 * 256 + k];
#pragma unroll
        for (int g = 0; g < 3; ++g) {
            float w = wx[k * 768 + g * 256 + tid];
            acc[g][0] = fmaf(f0, w, acc[g][0]);
            acc[g][1] = fmaf(f1, w, acc[g][1]);
            acc[g][2] = fmaf(f2, w, acc[g][2]);
            acc[g][3] = fmaf(f3, w, acc[g][3]);
        }
    }
#pragma unroll
    for (int r = 0; r < 4; ++r)
#pragma unroll
        for (int g = 0; g < 3; ++g)
            xg[(size_t)(r0 + r) * 768 + g * 256 + tid] = acc[g][r];
}

// ---------------------------------------------------------------------------
// GRU scan.  One block per batch row, 512 threads (8 waves).
// __launch_bounds__(512, 2): 256-VGPR budget so the 192 weight VGPRs
// (3 gates x 16 f16x8, compile-time-indexed) stay register-resident.
// 2 barriers/step (B1 of the old version is ordered by B3 already).
// ---------------------------------------------------------------------------
__global__ __launch_bounds__(512, 2) void k_gru(
    const float* __restrict__ xg,   // [512][768]
    const float* __restrict__ wh,   // [256][768]  [z|r|h]
    float* __restrict__ out)        // [16*32*256] seq ++ [16*256] state
{
    __shared__ float hf[256];
    __shared__ _Float16 hh[256];
    __shared__ _Float16 rhh[256];

    const int b = blockIdx.x;
    const int tid = threadIdx.x;
    const int lane = tid & 63, wv = tid >> 6;
    const int col = wv * 32 + (lane & 31);
    const int kc = lane >> 5;
    const int k0 = kc * 128;

    union W { f16x8 v; h2_t h[4]; };
    W wz[16], wr[16], wc[16];
#pragma unroll
    for (int j = 0; j < 16; ++j) {
#pragma unroll
        for (int e = 0; e < 8; ++e) {
            int k = k0 + 8 * j + e;
            wz[j].v[e] = (_Float16)wh[k * 768 + col];
            wr[j].v[e] = (_Float16)wh[k * 768 + col + 256];
            wc[j].v[e] = (_Float16)wh[k * 768 + col + 512];
        }
    }

    if (tid < 256) { hf[tid] = 0.f; hh[tid] = (_Float16)0.f; }
    __syncthreads();

    const f16x8* hh8 = (const f16x8*)hh;    // 32 x 16B
    const f16x8* rh8 = (const f16x8*)rhh;
    float* outb = out + (size_t)b * 32 * 256;

    const float* xrow0 = xg + (size_t)(b * 32) * 768;
    float xz = xrow0[col], xr = xrow0[col + 256], xh = xrow0[col + 512];

    for (int t = 0; t < 32; ++t) {
        // prefetch next timestep's x-gates (hides HBM/L2 latency)
        const int tn = (t < 31) ? t + 1 : 31;
        const float* xnext = xg + (size_t)(b * 32 + tn) * 768;
        float nxz = xnext[col], nxr = xnext[col + 256], nxh = xnext[col + 512];

        float az[4] = {0.f, 0.f, 0.f, 0.f};
        float ar[4] = {0.f, 0.f, 0.f, 0.f};
#pragma unroll
        for (int j = 0; j < 16; ++j) {
            W hv; hv.v = hh8[kc * 16 + j];       // broadcast b128 read
#pragma unroll
            for (int m = 0; m < 4; ++m) {
                az[j & 3] = fdot2(wz[j].h[m], hv.h[m], az[j & 3]);
                ar[j & 3] = fdot2(wr[j].h[m], hv.h[m], ar[j & 3]);
            }
        }
        float azs = (az[0] + az[1]) + (az[2] + az[3]);
        float ars = (ar[0] + ar[1]) + (ar[2] + ar[3]);
        azs += __shfl_xor(azs, 32, 64);
        ars += __shfl_xor(ars, 32, 64);
        float hold = hf[col];
        float z = 1.f / (1.f + __expf(-(azs + xz)));
        float r = 1.f / (1.f + __expf(-(ars + xr)));
        if (kc == 0) rhh[col] = (_Float16)(r * hold);
        __syncthreads();                          // B2: rhh visible

        float ah[4] = {0.f, 0.f, 0.f, 0.f};
#pragma unroll
        for (int j = 0; j < 16; ++j) {
            W rv; rv.v = rh8[kc * 16 + j];
#pragma unroll
            for (int m = 0; m < 4; ++m)
                ah[j & 3] = fdot2(wc[j].h[m], rv.h[m], ah[j & 3]);
        }
        float ahs = (ah[0] + ah[1]) + (ah[2] + ah[3]);
        ahs += __shfl_xor(ahs, 32, 64);
        float sx = ahs + xh;
        sx = fminf(fmaxf(sx, -15.f), 15.f);
        float e2 = __expf(2.f * sx);
        float hc = (e2 - 1.f) / (e2 + 1.f);       // tanh
        float hn = z * hold + (1.f - z) * hc;

        if (kc == 0) {
            hf[col] = hn;
            hh[col] = (_Float16)hn;
            outb[t * 256 + col] = hn;
            if (t == 31) out[16 * 32 * 256 + b * 256 + col] = hn;
        }
        xz = nxz; xr = nxr; xh = nxh;
        __syncthreads();                          // B3: h(t) visible
    }
}

// ---------------------------------------------------------------------------
extern "C" void kernel_launch(void* const* d_in, const int* in_sizes, int n_in,
                              void* d_out, int out_size, void* d_ws,
                              size_t ws_size, hipStream_t stream)
{
    const float* x  = (const float*)d_in[0];
    const float* w1 = (const float*)d_in[1];
    const float* b1 = (const float*)d_in[2];
    const float* w2 = (const float*)d_in[3];
    const float* b2 = (const float*)d_in[4];
    const float* dw = (const float*)d_in[5];
    const float* db = (const float*)d_in[6];
    const float* wx = (const float*)d_in[7];
    const float* wh = (const float*)d_in[8];
    const float* bg = (const float*)d_in[9];
    float* out = (float*)d_out;

    float* pooled = (float*)d_ws;                  // 512*64 f32
    float* xg = pooled + 512 * 64;                 // 512*768 f32
    f16x8* w2f = (f16x8*)(xg + 512 * 768);         // 9*4*64 f16x8

    k_w2prep<<<9, 256, 0, stream>>>(w2, w2f);
    k_conv<<<512, 512, 0, stream>>>(x, w1, b1, w2f, b2, pooled);
    k_dense<<<128, 256, 0, stream>>>(pooled, dw, db, wx, bg, xg);
    k_gru<<<16, 512, 0, stream>>>(xg, wh, out);
}

// Round 4
// 168.416 us; speedup vs baseline: 2.6655x; 1.0421x over previous
//
#include <hip/hip_runtime.h>
#include <hip/hip_bf16.h>

typedef _Float16 h2_t  __attribute__((ext_vector_type(2)));
typedef _Float16 f16x8 __attribute__((ext_vector_type(8)));
typedef float    f32x4 __attribute__((ext_vector_type(4)));

__device__ __forceinline__ float fdot2(h2_t a, h2_t b, float c) {
#if __has_builtin(__builtin_amdgcn_fdot2)
    return __builtin_amdgcn_fdot2(a, b, c, false);
#else
    return c + (float)a.x * (float)b.x + (float)a.y * (float)b.y;
#endif
}

__device__ __forceinline__ unsigned pack2(float lo, float hi) {
    union { h2_t h; unsigned u; } cv;
    cv.h.x = (_Float16)lo; cv.h.y = (_Float16)hi;
    return cv.u;
}

// ---------------------------------------------------------------------------
// Prep: w2 [9*32][64] f32 -> B-fragments for mfma_f32_16x16x32_f16.
// ---------------------------------------------------------------------------
__global__ __launch_bounds__(256) void k_w2prep(
    const float* __restrict__ w2, f16x8* __restrict__ w2f)
{
    int idx = blockIdx.x * 256 + threadIdx.x;   // 9*4*64 = 2304
    if (idx >= 9 * 4 * 64) return;
    int lane = idx & 63;
    int nt   = (idx >> 6) & 3;
    int tap  = idx >> 8;
    int oc = nt * 16 + (lane & 15);
    int c0 = (lane >> 4) * 8;
    f16x8 v;
#pragma unroll
    for (int j = 0; j < 8; ++j)
        v[j] = (_Float16)w2[(tap * 32 + c0 + j) * 64 + oc];
    w2f[idx] = v;
}

// ---------------------------------------------------------------------------
// Fused conv1(VALU) + conv2(MFMA) + global-average-pool.  1 block = 1 frame.
// ---------------------------------------------------------------------------
__global__ __launch_bounds__(512, 4) void k_conv(
    const float* __restrict__ x,    // [512][64][64][5]
    const float* __restrict__ w1,   // [3][3][5][32]
    const float* __restrict__ b1,   // [32]
    const f16x8* __restrict__ w2f,  // [9][4][64] B-frags
    const float* __restrict__ b2,   // [64]
    float* __restrict__ pooled)     // [512][64]
{
    __shared__ _Float16 c1s[32 * 33 * 32];   // [ih][iw(+pad)][c] 67.6 KB
    __shared__ float pl[8 * 64];

    const int n = blockIdx.x;
    const int tid = threadIdx.x;
    const int lane = tid & 63, wv = tid >> 6;

    {   // zero the iw==32 pad column
        int r = tid >> 4, d = tid & 15;
        ((unsigned*)c1s)[(r * 33 + 32) * 16 + d] = 0u;
    }

    const float* xf = x + (size_t)n * 20480;

    for (int pp = 0; pp < 2; ++pp) {
        int p = tid + pp * 512;
        int oh = p >> 5, ow = p & 31;
        float acc[32];
#pragma unroll
        for (int oc = 0; oc < 32; ++oc) acc[oc] = b1[oc];
#pragma unroll
        for (int ky = 0; ky < 3; ++ky) {
            int ih = 2 * oh + ky;
            if (ih < 64) {
                const float* rb = xf + (ih * 64 + 2 * ow) * 5;
                float xv[15];
                const float2* rb2 = (const float2*)rb;
#pragma unroll
                for (int q = 0; q < 5; ++q) {
                    float2 v = rb2[q];
                    xv[2 * q] = v.x; xv[2 * q + 1] = v.y;
                }
                if (ow < 31) {
                    float2 v5 = rb2[5], v6 = rb2[6];
                    xv[10] = v5.x; xv[11] = v5.y;
                    xv[12] = v6.x; xv[13] = v6.y;
                    xv[14] = rb[14];
                } else {
                    xv[10] = xv[11] = xv[12] = xv[13] = xv[14] = 0.f;
                }
#pragma unroll
                for (int q = 0; q < 15; ++q) {
                    float v = xv[q];
                    const float* wp = w1 + (ky * 15 + q) * 32;
#pragma unroll
                    for (int oc = 0; oc < 32; ++oc)
                        acc[oc] = fmaf(v, wp[oc], acc[oc]);
                }
            }
        }
        unsigned* dst = (unsigned*)&c1s[(oh * 33 + ow) * 32];
#pragma unroll
        for (int j = 0; j < 16; ++j)
            dst[j] = pack2(fmaxf(acc[2 * j], 0.f), fmaxf(acc[2 * j + 1], 0.f));
    }
    __syncthreads();

    // conv2 as implicit GEMM via MFMA: M=256 px, N=64 oc, K=9x32
    f32x4 acc2[2][4];
#pragma unroll
    for (int mt = 0; mt < 2; ++mt)
#pragma unroll
        for (int nt = 0; nt < 4; ++nt) acc2[mt][nt] = f32x4{0.f, 0.f, 0.f, 0.f};

    const int owl = lane & 15;
    const int cb = (lane >> 4) * 8;
#pragma unroll
    for (int tap = 0; tap < 9; ++tap) {
        const int ky = tap / 3, kx = tap % 3;
        f16x8 bf[4];
#pragma unroll
        for (int nt = 0; nt < 4; ++nt)
            bf[nt] = w2f[(tap * 4 + nt) * 64 + lane];
#pragma unroll
        for (int mt = 0; mt < 2; ++mt) {
            int oh2 = wv + mt * 8;
            int ih = 2 * oh2 + ky;
            if (ih < 32) {
                int iw = 2 * owl + kx;
                f16x8 af = *(const f16x8*)&c1s[(ih * 33 + iw) * 32 + cb];
#pragma unroll
                for (int nt = 0; nt < 4; ++nt)
                    acc2[mt][nt] = __builtin_amdgcn_mfma_f32_16x16x32_f16(
                        af, bf[nt], acc2[mt][nt], 0, 0, 0);
            }
        }
    }

#pragma unroll
    for (int nt = 0; nt < 4; ++nt) {
        float b = b2[nt * 16 + owl];
        float s = 0.f;
#pragma unroll
        for (int mt = 0; mt < 2; ++mt)
#pragma unroll
            for (int r = 0; r < 4; ++r)
                s += fmaxf(acc2[mt][nt][r] + b, 0.f);
        s += __shfl_xor(s, 16, 64);
        s += __shfl_xor(s, 32, 64);
        if (lane < 16) pl[wv * 64 + nt * 16 + lane] = s;
    }
    __syncthreads();
    if (tid < 64) {
        float s = 0.f;
#pragma unroll
        for (int w = 0; w < 8; ++w) s += pl[w * 64 + tid];
        pooled[n * 64 + tid] = s * (1.0f / 256.0f);
    }
}

// ---------------------------------------------------------------------------
// Dense: feats = relu(pooled @ dw + db);  xg = feats @ wx + b_gru.
// ---------------------------------------------------------------------------
__global__ __launch_bounds__(256) void k_dense(
    const float* __restrict__ pooled,  // [512][64]
    const float* __restrict__ dw,      // [64][256]
    const float* __restrict__ db,      // [256]
    const float* __restrict__ wx,      // [256][768]
    const float* __restrict__ bg,      // [768]
    float* __restrict__ xg)            // [512][768]
{
    __shared__ float ps[4 * 64];
    __shared__ float fs[4 * 256];
    const int tid = threadIdx.x;
    const int r0 = blockIdx.x * 4;

    ps[tid & 255] = pooled[r0 * 64 + (tid & 255)];
    __syncthreads();

    {
        float a0 = db[tid], a1 = a0, a2 = a0, a3 = a0;
        for (int k = 0; k < 64; ++k) {
            float w = dw[k * 256 + tid];
            a0 = fmaf(ps[0 * 64 + k], w, a0);
            a1 = fmaf(ps[1 * 64 + k], w, a1);
            a2 = fmaf(ps[2 * 64 + k], w, a2);
            a3 = fmaf(ps[3 * 64 + k], w, a3);
        }
        fs[0 * 256 + tid] = fmaxf(a0, 0.f);
        fs[1 * 256 + tid] = fmaxf(a1, 0.f);
        fs[2 * 256 + tid] = fmaxf(a2, 0.f);
        fs[3 * 256 + tid] = fmaxf(a3, 0.f);
    }
    __syncthreads();

    float acc[3][4];
#pragma unroll
    for (int g = 0; g < 3; ++g) {
        float b = bg[g * 256 + tid];
#pragma unroll
        for (int r = 0; r < 4; ++r) acc[g][r] = b;
    }
    for (int k = 0; k < 256; ++k) {
        float f0 = fs[0 * 256 + k], f1 = fs[1 * 256 + k];
        float f2 = fs[2 * 256 + k], f3 = fs[3 * 256 + k];
#pragma unroll
        for (int g = 0; g < 3; ++g) {
            float w = wx[k * 768 + g * 256 + tid];
            acc[g][0] = fmaf(f0, w, acc[g][0]);
            acc[g][1] = fmaf(f1, w, acc[g][1]);
            acc[g][2] = fmaf(f2, w, acc[g][2]);
            acc[g][3] = fmaf(f3, w, acc[g][3]);
        }
    }
#pragma unroll
    for (int r = 0; r < 4; ++r)
#pragma unroll
        for (int g = 0; g < 3; ++g)
            xg[(size_t)(r0 + r) * 768 + g * 256 + tid] = acc[g][r];
}

// ---------------------------------------------------------------------------
// GRU scan.  One block per batch row, 1024 threads (16 waves).
// Thread (col, kc): col = wv*16 + (lane&15)  (256 cols / 16 waves),
//                   kc  = lane>>4            (4 k-chunks of 64).
// Per-thread weights: 3 gates x 32 h2 = 96 VGPRs -> fits the 128-VGPR cap
// the allocator picks (R3 showed launch_bounds can't unlock 256; 192-VGPR
// weights spilled to scratch and the kernel ran at scratch latency).
// Reduction: shfl_xor 16 + 32.  2 barriers/step.
// ---------------------------------------------------------------------------
__global__ __launch_bounds__(1024, 4) void k_gru(
    const float* __restrict__ xg,   // [512][768]
    const float* __restrict__ wh,   // [256][768]  [z|r|h]
    float* __restrict__ out)        // [16*32*256] seq ++ [16*256] state
{
    __shared__ float hf[256];
    __shared__ _Float16 hh[256];
    __shared__ _Float16 rhh[256];

    const int b = blockIdx.x;
    const int tid = threadIdx.x;
    const int lane = tid & 63, wv = tid >> 6;
    const int col = wv * 16 + (lane & 15);
    const int kc = lane >> 4;          // 0..3
    const int k0 = kc * 64;

    h2_t wz[32], wr[32], wc[32];       // 96 VGPRs, statically indexed
#pragma unroll
    for (int j = 0; j < 32; ++j) {
        int k = k0 + 2 * j;
        wz[j] = h2_t{(_Float16)wh[k * 768 + col],
                     (_Float16)wh[(k + 1) * 768 + col]};
        wr[j] = h2_t{(_Float16)wh[k * 768 + col + 256],
                     (_Float16)wh[(k + 1) * 768 + col + 256]};
        wc[j] = h2_t{(_Float16)wh[k * 768 + col + 512],
                     (_Float16)wh[(k + 1) * 768 + col + 512]};
    }

    if (tid < 256) { hf[tid] = 0.f; hh[tid] = (_Float16)0.f; }
    __syncthreads();

    const f16x8* hh8 = (const f16x8*)hh;    // 32 x 16B
    const f16x8* rh8 = (const f16x8*)rhh;
    float* outb = out + (size_t)b * 32 * 256;

    for (int t = 0; t < 32; ++t) {
        const float* xrow = xg + (size_t)(b * 32 + t) * 768;
        float xz = xrow[col], xr = xrow[col + 256], xh = xrow[col + 512];
        float hold = hf[col];

        float az0 = 0.f, az1 = 0.f, ar0 = 0.f, ar1 = 0.f;
#pragma unroll
        for (int j = 0; j < 8; ++j) {
            f16x8 hv = hh8[kc * 8 + j];          // broadcast b128 read
            h2_t h0 = __builtin_shufflevector(hv, hv, 0, 1);
            h2_t h1 = __builtin_shufflevector(hv, hv, 2, 3);
            h2_t h2v = __builtin_shufflevector(hv, hv, 4, 5);
            h2_t h3 = __builtin_shufflevector(hv, hv, 6, 7);
            az0 = fdot2(wz[4 * j + 0], h0, az0);
            az1 = fdot2(wz[4 * j + 1], h1, az1);
            az0 = fdot2(wz[4 * j + 2], h2v, az0);
            az1 = fdot2(wz[4 * j + 3], h3, az1);
            ar0 = fdot2(wr[4 * j + 0], h0, ar0);
            ar1 = fdot2(wr[4 * j + 1], h1, ar1);
            ar0 = fdot2(wr[4 * j + 2], h2v, ar0);
            ar1 = fdot2(wr[4 * j + 3], h3, ar1);
        }
        float azs = az0 + az1;
        float ars = ar0 + ar1;
        azs += __shfl_xor(azs, 16, 64);
        azs += __shfl_xor(azs, 32, 64);
        ars += __shfl_xor(ars, 16, 64);
        ars += __shfl_xor(ars, 32, 64);
        float z = 1.f / (1.f + __expf(-(azs + xz)));
        float r = 1.f / (1.f + __expf(-(ars + xr)));
        if (kc == 0) rhh[col] = (_Float16)(r * hold);
        __syncthreads();                          // B2: rhh visible

        float ah0 = 0.f, ah1 = 0.f;
#pragma unroll
        for (int j = 0; j < 8; ++j) {
            f16x8 rv = rh8[kc * 8 + j];
            h2_t r0v = __builtin_shufflevector(rv, rv, 0, 1);
            h2_t r1v = __builtin_shufflevector(rv, rv, 2, 3);
            h2_t r2v = __builtin_shufflevector(rv, rv, 4, 5);
            h2_t r3v = __builtin_shufflevector(rv, rv, 6, 7);
            ah0 = fdot2(wc[4 * j + 0], r0v, ah0);
            ah1 = fdot2(wc[4 * j + 1], r1v, ah1);
            ah0 = fdot2(wc[4 * j + 2], r2v, ah0);
            ah1 = fdot2(wc[4 * j + 3], r3v, ah1);
        }
        float ahs = ah0 + ah1;
        ahs += __shfl_xor(ahs, 16, 64);
        ahs += __shfl_xor(ahs, 32, 64);
        float sx = ahs + xh;
        sx = fminf(fmaxf(sx, -15.f), 15.f);
        float e2 = __expf(2.f * sx);
        float hc = (e2 - 1.f) / (e2 + 1.f);       // tanh
        float hn = z * hold + (1.f - z) * hc;

        if (kc == 0) {
            hf[col] = hn;
            hh[col] = (_Float16)hn;
            outb[t * 256 + col] = hn;
            if (t == 31) out[16 * 32 * 256 + b * 256 + col] = hn;
        }
        __syncthreads();                          // B3: h(t) visible
    }
}

// ---------------------------------------------------------------------------
extern "C" void kernel_launch(void* const* d_in, const int* in_sizes, int n_in,
                              void* d_out, int out_size, void* d_ws,
                              size_t ws_size, hipStream_t stream)
{
    const float* x  = (const float*)d_in[0];
    const float* w1 = (const float*)d_in[1];
    const float* b1 = (const float*)d_in[2];
    const float* w2 = (const float*)d_in[3];
    const float* b2 = (const float*)d_in[4];
    const float* dw = (const float*)d_in[5];
    const float* db = (const float*)d_in[6];
    const float* wx = (const float*)d_in[7];
    const float* wh = (const float*)d_in[8];
    const float* bg = (const float*)d_in[9];
    float* out = (float*)d_out;

    float* pooled = (float*)d_ws;                  // 512*64 f32
    float* xg = pooled + 512 * 64;                 // 512*768 f32
    f16x8* w2f = (f16x8*)(xg + 512 * 768);         // 9*4*64 f16x8

    k_w2prep<<<9, 256, 0, stream>>>(w2, w2f);
    k_conv<<<512, 512, 0, stream>>>(x, w1, b1, w2f, b2, pooled);
    k_dense<<<128, 256, 0, stream>>>(pooled, dw, db, wx, bg, xg);
    k_gru<<<16, 1024, 0, stream>>>(xg, wh, out);
}

// Round 5
// 131.854 us; speedup vs baseline: 3.4046x; 1.2773x over previous
//
#include <hip/hip_runtime.h>
#include <hip/hip_bf16.h>

typedef _Float16 h2_t  __attribute__((ext_vector_type(2)));
typedef _Float16 f16x8 __attribute__((ext_vector_type(8)));
typedef float    f32x4 __attribute__((ext_vector_type(4)));

__device__ __forceinline__ float fdot2(h2_t a, h2_t b, float c) {
#if __has_builtin(__builtin_amdgcn_fdot2)
    return __builtin_amdgcn_fdot2(a, b, c, false);
#else
    return c + (float)a.x * (float)b.x + (float)a.y * (float)b.y;
#endif
}

__device__ __forceinline__ unsigned pack2(float lo, float hi) {
    union { h2_t h; unsigned u; } cv;
    cv.h.x = (_Float16)lo; cv.h.y = (_Float16)hi;
    return cv.u;
}

// ---------------------------------------------------------------------------
// Prep A: w2 [9*32][64] f32 -> B-fragments for mfma_f32_16x16x32_f16.
// ---------------------------------------------------------------------------
__global__ __launch_bounds__(256) void k_w2prep(
    const float* __restrict__ w2, f16x8* __restrict__ w2f)
{
    int idx = blockIdx.x * 256 + threadIdx.x;   // 9*4*64 = 2304
    if (idx >= 9 * 4 * 64) return;
    int lane = idx & 63;
    int nt   = (idx >> 6) & 3;
    int tap  = idx >> 8;
    int oc = nt * 16 + (lane & 15);
    int c0 = (lane >> 4) * 8;
    f16x8 v;
#pragma unroll
    for (int j = 0; j < 8; ++j)
        v[j] = (_Float16)w2[(tap * 32 + c0 + j) * 64 + oc];
    w2f[idx] = v;
}

// ---------------------------------------------------------------------------
// Prep B: wh [256][768] f32 -> whT [768 cols][256 k] f16 (k-contiguous).
// One block per output col; 256 threads each convert one k.
// ---------------------------------------------------------------------------
__global__ __launch_bounds__(256) void k_whprep(
    const float* __restrict__ wh, _Float16* __restrict__ whT)
{
    int c = blockIdx.x;            // 0..767
    int k = threadIdx.x;           // 0..255
    whT[c * 256 + k] = (_Float16)wh[k * 768 + c];
}

// ---------------------------------------------------------------------------
// Fused conv1(VALU) + conv2(MFMA) + global-average-pool.  1 block = 1 frame.
// ---------------------------------------------------------------------------
__global__ __launch_bounds__(512, 4) void k_conv(
    const float* __restrict__ x,    // [512][64][64][5]
    const float* __restrict__ w1,   // [3][3][5][32]
    const float* __restrict__ b1,   // [32]
    const f16x8* __restrict__ w2f,  // [9][4][64] B-frags
    const float* __restrict__ b2,   // [64]
    float* __restrict__ pooled)     // [512][64]
{
    __shared__ _Float16 c1s[32 * 33 * 32];   // [ih][iw(+pad)][c] 67.6 KB
    __shared__ float pl[8 * 64];

    const int n = blockIdx.x;
    const int tid = threadIdx.x;
    const int lane = tid & 63, wv = tid >> 6;

    {   // zero the iw==32 pad column
        int r = tid >> 4, d = tid & 15;
        ((unsigned*)c1s)[(r * 33 + 32) * 16 + d] = 0u;
    }

    const float* xf = x + (size_t)n * 20480;

    for (int pp = 0; pp < 2; ++pp) {
        int p = tid + pp * 512;
        int oh = p >> 5, ow = p & 31;
        float acc[32];
#pragma unroll
        for (int oc = 0; oc < 32; ++oc) acc[oc] = b1[oc];
#pragma unroll
        for (int ky = 0; ky < 3; ++ky) {
            int ih = 2 * oh + ky;
            if (ih < 64) {
                const float* rb = xf + (ih * 64 + 2 * ow) * 5;
                float xv[15];
                const float2* rb2 = (const float2*)rb;
#pragma unroll
                for (int q = 0; q < 5; ++q) {
                    float2 v = rb2[q];
                    xv[2 * q] = v.x; xv[2 * q + 1] = v.y;
                }
                if (ow < 31) {
                    float2 v5 = rb2[5], v6 = rb2[6];
                    xv[10] = v5.x; xv[11] = v5.y;
                    xv[12] = v6.x; xv[13] = v6.y;
                    xv[14] = rb[14];
                } else {
                    xv[10] = xv[11] = xv[12] = xv[13] = xv[14] = 0.f;
                }
#pragma unroll
                for (int q = 0; q < 15; ++q) {
                    float v = xv[q];
                    const float* wp = w1 + (ky * 15 + q) * 32;
#pragma unroll
                    for (int oc = 0; oc < 32; ++oc)
                        acc[oc] = fmaf(v, wp[oc], acc[oc]);
                }
            }
        }
        unsigned* dst = (unsigned*)&c1s[(oh * 33 + ow) * 32];
#pragma unroll
        for (int j = 0; j < 16; ++j)
            dst[j] = pack2(fmaxf(acc[2 * j], 0.f), fmaxf(acc[2 * j + 1], 0.f));
    }
    __syncthreads();

    // conv2 as implicit GEMM via MFMA: M=256 px, N=64 oc, K=9x32
    f32x4 acc2[2][4];
#pragma unroll
    for (int mt = 0; mt < 2; ++mt)
#pragma unroll
        for (int nt = 0; nt < 4; ++nt) acc2[mt][nt] = f32x4{0.f, 0.f, 0.f, 0.f};

    const int owl = lane & 15;
    const int cb = (lane >> 4) * 8;
#pragma unroll
    for (int tap = 0; tap < 9; ++tap) {
        const int ky = tap / 3, kx = tap % 3;
        f16x8 bf[4];
#pragma unroll
        for (int nt = 0; nt < 4; ++nt)
            bf[nt] = w2f[(tap * 4 + nt) * 64 + lane];
#pragma unroll
        for (int mt = 0; mt < 2; ++mt) {
            int oh2 = wv + mt * 8;
            int ih = 2 * oh2 + ky;
            if (ih < 32) {
                int iw = 2 * owl + kx;
                f16x8 af = *(const f16x8*)&c1s[(ih * 33 + iw) * 32 + cb];
#pragma unroll
                for (int nt = 0; nt < 4; ++nt)
                    acc2[mt][nt] = __builtin_amdgcn_mfma_f32_16x16x32_f16(
                        af, bf[nt], acc2[mt][nt], 0, 0, 0);
            }
        }
    }

#pragma unroll
    for (int nt = 0; nt < 4; ++nt) {
        float b = b2[nt * 16 + owl];
        float s = 0.f;
#pragma unroll
        for (int mt = 0; mt < 2; ++mt)
#pragma unroll
            for (int r = 0; r < 4; ++r)
                s += fmaxf(acc2[mt][nt][r] + b, 0.f);
        s += __shfl_xor(s, 16, 64);
        s += __shfl_xor(s, 32, 64);
        if (lane < 16) pl[wv * 64 + nt * 16 + lane] = s;
    }
    __syncthreads();
    if (tid < 64) {
        float s = 0.f;
#pragma unroll
        for (int w = 0; w < 8; ++w) s += pl[w * 64 + tid];
        pooled[n * 64 + tid] = s * (1.0f / 256.0f);
    }
}

// ---------------------------------------------------------------------------
// Dense: feats = relu(pooled @ dw + db);  xg = feats @ wx + b_gru.
// ---------------------------------------------------------------------------
__global__ __launch_bounds__(256) void k_dense(
    const float* __restrict__ pooled,  // [512][64]
    const float* __restrict__ dw,      // [64][256]
    const float* __restrict__ db,      // [256]
    const float* __restrict__ wx,      // [256][768]
    const float* __restrict__ bg,      // [768]
    float* __restrict__ xg)            // [512][768]
{
    __shared__ float ps[4 * 64];
    __shared__ float fs[4 * 256];
    const int tid = threadIdx.x;
    const int r0 = blockIdx.x * 4;

    ps[tid & 255] = pooled[r0 * 64 + (tid & 255)];
    __syncthreads();

    {
        float a0 = db[tid], a1 = a0, a2 = a0, a3 = a0;
        for (int k = 0; k < 64; ++k) {
            float w = dw[k * 256 + tid];
            a0 = fmaf(ps[0 * 64 + k], w, a0);
            a1 = fmaf(ps[1 * 64 + k], w, a1);
            a2 = fmaf(ps[2 * 64 + k], w, a2);
            a3 = fmaf(ps[3 * 64 + k], w, a3);
        }
        fs[0 * 256 + tid] = fmaxf(a0, 0.f);
        fs[1 * 256 + tid] = fmaxf(a1, 0.f);
        fs[2 * 256 + tid] = fmaxf(a2, 0.f);
        fs[3 * 256 + tid] = fmaxf(a3, 0.f);
    }
    __syncthreads();

    float acc[3][4];
#pragma unroll
    for (int g = 0; g < 3; ++g) {
        float b = bg[g * 256 + tid];
#pragma unroll
        for (int r = 0; r < 4; ++r) acc[g][r] = b;
    }
    for (int k = 0; k < 256; ++k) {
        float f0 = fs[0 * 256 + k], f1 = fs[1 * 256 + k];
        float f2 = fs[2 * 256 + k], f3 = fs[3 * 256 + k];
#pragma unroll
        for (int g = 0; g < 3; ++g) {
            float w = wx[k * 768 + g * 256 + tid];
            acc[g][0] = fmaf(f0, w, acc[g][0]);
            acc[g][1] = fmaf(f1, w, acc[g][1]);
            acc[g][2] = fmaf(f2, w, acc[g][2]);
            acc[g][3] = fmaf(f3, w, acc[g][3]);
        }
    }
#pragma unroll
    for (int r = 0; r < 4; ++r)
#pragma unroll
        for (int g = 0; g < 3; ++g)
            xg[(size_t)(r0 + r) * 768 + g * 256 + tid] = acc[g][r];
}

// ---------------------------------------------------------------------------
// GRU scan.  One block per batch row, 512 threads (8 waves).
// col = wv*32 + (lane&31); kc = lane>>5 selects 128-k chunk.
// Weights register-resident f16 (3 x 64 h2 = 192 VGPRs, statically indexed).
// amdgpu_waves_per_eu(2,2): pin the occupancy target to 2 waves/EU so the
// allocator gets the 256-VGPR budget (launch_bounds min alone was overridden
// by the backend's memory-bound occupancy heuristic in R2-R4 -> spills).
// ---------------------------------------------------------------------------
__global__ __attribute__((amdgpu_flat_work_group_size(512, 512),
                          amdgpu_waves_per_eu(2, 2)))
void k_gru(
    const _Float16* __restrict__ whT,  // [768 cols][256 k] f16
    const float* __restrict__ xg,      // [512][768]
    float* __restrict__ out)           // [16*32*256] seq ++ [16*256] state
{
    __shared__ float hf[256];
    __shared__ _Float16 hh[256];
    __shared__ _Float16 rhh[256];

    const int b = blockIdx.x;
    const int tid = threadIdx.x;
    const int lane = tid & 63, wv = tid >> 6;
    const int col = wv * 32 + (lane & 31);
    const int kc = lane >> 5;          // 0 or 1
    const int k0 = kc * 128;

    // ---- weight init: k-contiguous b128 loads, 48 total ----
    h2_t wz[64], wr[64], wc[64];       // 192 VGPRs, statically indexed
    {
        const f16x8* pz = (const f16x8*)(whT + (size_t)col * 256 + k0);
        const f16x8* pr = (const f16x8*)(whT + (size_t)(col + 256) * 256 + k0);
        const f16x8* pc = (const f16x8*)(whT + (size_t)(col + 512) * 256 + k0);
#pragma unroll
        for (int j = 0; j < 16; ++j) {
            f16x8 vz = pz[j], vr = pr[j], vc = pc[j];
#pragma unroll
            for (int m = 0; m < 4; ++m) {
                wz[4 * j + m] = __builtin_shufflevector(vz, vz, 0, 1);
                wr[4 * j + m] = __builtin_shufflevector(vr, vr, 0, 1);
                wc[4 * j + m] = __builtin_shufflevector(vc, vc, 0, 1);
                vz = __builtin_shufflevector(vz, vz, 2, 3, 4, 5, 6, 7, 0, 1);
                vr = __builtin_shufflevector(vr, vr, 2, 3, 4, 5, 6, 7, 0, 1);
                vc = __builtin_shufflevector(vc, vc, 2, 3, 4, 5, 6, 7, 0, 1);
            }
        }
    }

    if (tid < 256) { hf[tid] = 0.f; hh[tid] = (_Float16)0.f; }
    __syncthreads();

    const f16x8* hh8 = (const f16x8*)hh;    // 32 x 16B
    const f16x8* rh8 = (const f16x8*)rhh;
    float* outb = out + (size_t)b * 32 * 256;

    const float* xrow0 = xg + (size_t)(b * 32) * 768;
    float xz = xrow0[col], xr = xrow0[col + 256], xh = xrow0[col + 512];

    for (int t = 0; t < 32; ++t) {
        const int tn = (t < 31) ? t + 1 : 31;
        const float* xnext = xg + (size_t)(b * 32 + tn) * 768;
        float nxz = xnext[col], nxr = xnext[col + 256], nxh = xnext[col + 512];

        float az0 = 0.f, az1 = 0.f, ar0 = 0.f, ar1 = 0.f;
#pragma unroll
        for (int j = 0; j < 16; ++j) {
            f16x8 hv = hh8[kc * 16 + j];         // broadcast b128 read
            h2_t h0 = __builtin_shufflevector(hv, hv, 0, 1);
            h2_t h1 = __builtin_shufflevector(hv, hv, 2, 3);
            h2_t h2v = __builtin_shufflevector(hv, hv, 4, 5);
            h2_t h3 = __builtin_shufflevector(hv, hv, 6, 7);
            az0 = fdot2(wz[4 * j + 0], h0, az0);
            az1 = fdot2(wz[4 * j + 1], h1, az1);
            az0 = fdot2(wz[4 * j + 2], h2v, az0);
            az1 = fdot2(wz[4 * j + 3], h3, az1);
            ar0 = fdot2(wr[4 * j + 0], h0, ar0);
            ar1 = fdot2(wr[4 * j + 1], h1, ar1);
            ar0 = fdot2(wr[4 * j + 2], h2v, ar0);
            ar1 = fdot2(wr[4 * j + 3], h3, ar1);
        }
        float azs = az0 + az1;
        float ars = ar0 + ar1;
        azs += __shfl_xor(azs, 32, 64);
        ars += __shfl_xor(ars, 32, 64);
        float hold = hf[col];
        float z = 1.f / (1.f + __expf(-(azs + xz)));
        float r = 1.f / (1.f + __expf(-(ars + xr)));
        if (kc == 0) rhh[col] = (_Float16)(r * hold);
        __syncthreads();                          // B2: rhh visible

        float ah0 = 0.f, ah1 = 0.f;
#pragma unroll
        for (int j = 0; j < 16; ++j) {
            f16x8 rv = rh8[kc * 16 + j];
            h2_t r0v = __builtin_shufflevector(rv, rv, 0, 1);
            h2_t r1v = __builtin_shufflevector(rv, rv, 2, 3);
            h2_t r2v = __builtin_shufflevector(rv, rv, 4, 5);
            h2_t r3v = __builtin_shufflevector(rv, rv, 6, 7);
            ah0 = fdot2(wc[4 * j + 0], r0v, ah0);
            ah1 = fdot2(wc[4 * j + 1], r1v, ah1);
            ah0 = fdot2(wc[4 * j + 2], r2v, ah0);
            ah1 = fdot2(wc[4 * j + 3], r3v, ah1);
        }
        float ahs = ah0 + ah1;
        ahs += __shfl_xor(ahs, 32, 64);
        float sx = ahs + xh;
        sx = fminf(fmaxf(sx, -15.f), 15.f);
        float e2 = __expf(2.f * sx);
        float hc = (e2 - 1.f) / (e2 + 1.f);       // tanh
        float hn = z * hold + (1.f - z) * hc;

        if (kc == 0) {
            hf[col] = hn;
            hh[col] = (_Float16)hn;
            outb[t * 256 + col] = hn;
            if (t == 31) out[16 * 32 * 256 + b * 256 + col] = hn;
        }
        xz = nxz; xr = nxr; xh = nxh;
        __syncthreads();                          // B3: h(t) visible
    }
}

// ---------------------------------------------------------------------------
extern "C" void kernel_launch(void* const* d_in, const int* in_sizes, int n_in,
                              void* d_out, int out_size, void* d_ws,
                              size_t ws_size, hipStream_t stream)
{
    const float* x  = (const float*)d_in[0];
    const float* w1 = (const float*)d_in[1];
    const float* b1 = (const float*)d_in[2];
    const float* w2 = (const float*)d_in[3];
    const float* b2 = (const float*)d_in[4];
    const float* dw = (const float*)d_in[5];
    const float* db = (const float*)d_in[6];
    const float* wx = (const float*)d_in[7];
    const float* wh = (const float*)d_in[8];
    const float* bg = (const float*)d_in[9];
    float* out = (float*)d_out;

    float* pooled = (float*)d_ws;                  // 512*64 f32
    float* xg = pooled + 512 * 64;                 // 512*768 f32
    f16x8* w2f = (f16x8*)(xg + 512 * 768);         // 9*4*64 f16x8 (36.9 KB)
    _Float16* whT = (_Float16*)(w2f + 9 * 4 * 64); // 768*256 f16 (384 KB)

    k_w2prep<<<9, 256, 0, stream>>>(w2, w2f);
    k_whprep<<<768, 256, 0, stream>>>(wh, whT);
    k_conv<<<512, 512, 0, stream>>>(x, w1, b1, w2f, b2, pooled);
    k_dense<<<128, 256, 0, stream>>>(pooled, dw, db, wx, bg, xg);
    k_gru<<<16, 512, 0, stream>>>(whT, xg, out);
}